// Round 12
// baseline (769.568 us; speedup 1.0000x reference)
//
#include <hip/hip_runtime.h>
#include <hip/hip_bf16.h>

// Problem constants (match reference)
#define DD 128      // feature dim
#define AA 4        // edge attr dim
#define HH 2        // heads

typedef short short8 __attribute__((ext_vector_type(8)));
typedef float f32x4 __attribute__((ext_vector_type(4)));

// bf16 pack/unpack (RNE)
__device__ inline unsigned short f2bf(float f) {
    unsigned u = __float_as_uint(f);
    unsigned r = (u + 0x7fffu + ((u >> 16) & 1u)) >> 16;
    return (unsigned short)r;
}
__device__ inline float4 unpack_bf16x4(uint2 v) {
    float4 r;
    r.x = __uint_as_float(v.x << 16);
    r.y = __uint_as_float(v.x & 0xffff0000u);
    r.z = __uint_as_float(v.y << 16);
    r.w = __uint_as_float(v.y & 0xffff0000u);
    return r;
}
__device__ inline uint2 pack_bf16x4(float a, float b, float c, float d) {
    uint2 p;
    p.x = (unsigned)f2bf(a) | ((unsigned)f2bf(b) << 16);
    p.y = (unsigned)f2bf(c) | ((unsigned)f2bf(d) << 16);
    return p;
}

// ---------------------------------------------------------------------------
// CSR build, pass 1: histogram + per-edge rank in ONE atomic pass.
// ---------------------------------------------------------------------------

__global__ void rank_kernel(const int* __restrict__ dst, int* __restrict__ cnt,
                            int* __restrict__ rank, int E) {
    int e = blockIdx.x * blockDim.x + threadIdx.x;
    if (e < E) rank[e] = atomicAdd(&cnt[dst[e]], 1);
}

// scan1: per-1024-chunk sums; block 0 also inits y = fb
__global__ __launch_bounds__(256) void scan1(const int* __restrict__ cnt,
                                             int* __restrict__ bsum, int N,
                                             float* __restrict__ y,
                                             const float* __restrict__ fb) {
    __shared__ int wsh[4];
    int b = blockIdx.x, t = threadIdx.x;
    int lane = t & 63, w = t >> 6;
    if (b == 0 && t < 128) y[t] = fb[0];
    int base = b * 1024;
    int v = 0;
    #pragma unroll
    for (int i = 0; i < 4; ++i) {
        int idx = base + i * 256 + t;
        v += (idx < N) ? cnt[idx] : 0;
    }
    #pragma unroll
    for (int o = 32; o; o >>= 1) v += __shfl_xor(v, o);
    if (lane == 0) wsh[w] = v;
    __syncthreads();
    if (t == 0) bsum[b] = wsh[0] + wsh[1] + wsh[2] + wsh[3];
}

// scan3: final per-element exclusive prefix; each block wave-scans bsum (NB<=64)
__global__ __launch_bounds__(256) void scan3(const int* __restrict__ cnt,
                                             const int* __restrict__ bsum,
                                             int* __restrict__ row_off,
                                             int N, int NB, int E) {
    __shared__ int wtot[4];
    __shared__ int carry;
    int b = blockIdx.x, t = threadIdx.x;
    int lane = t & 63, w = t >> 6;
    if (w == 0) {
        int v = (lane < NB) ? bsum[lane] : 0;
        int x = v;
        #pragma unroll
        for (int o = 1; o < 64; o <<= 1) {
            int u = __shfl_up(x, o);
            if (lane >= o) x += u;
        }
        int base = (b == 0) ? 0 : __shfl(x, b - 1);
        if (lane == 0) carry = base;
    }
    if (b == 0 && t == 0) row_off[N] = E;
    __syncthreads();
    int base = b * 1024;
    #pragma unroll
    for (int it = 0; it < 4; ++it) {
        int idx = base + it * 256 + t;
        int v = (idx < N) ? cnt[idx] : 0;
        int x = v;
        #pragma unroll
        for (int o = 1; o < 64; o <<= 1) {
            int u = __shfl_up(x, o);
            if (lane >= o) x += u;
        }
        if (lane == 63) wtot[w] = x;
        __syncthreads();
        int woff = 0;
        for (int i = 0; i < w; ++i) woff += wtot[i];
        int c = carry;
        __syncthreads();
        if (t == 255) carry = c + woff + x;
        int ex = c + woff + x - v;
        if (idx < N) row_off[idx] = ex;
        __syncthreads();
    }
}

// CSR build, pass 2: one random 8B write of (edge id, src) per edge.
__global__ void perm_kernel(const int* __restrict__ src, const int* __restrict__ dst,
                            const int* __restrict__ rank,
                            const int* __restrict__ row_off,
                            int2* __restrict__ perm2, int E) {
    int e = blockIdx.x * blockDim.x + threadIdx.x;
    if (e >= E) return;
    int2 v; v.x = e; v.y = src[e];
    perm2[row_off[dst[e]] + rank[e]] = v;
}

// ---------------------------------------------------------------------------
// Fused prep: edge transform (all 3 layers, CSR-ordered) + asrc extraction +
// pack_a0 + pack_w3, via blockIdx range split.
// ---------------------------------------------------------------------------

__device__ inline void edge_stage(const float4& ev, const float* __restrict__ linE,
                                  const float* __restrict__ att, float2& ae, float4& enext) {
    float eh[8];
    #pragma unroll
    for (int c = 0; c < 8; ++c)
        eh[c] = ev.x * linE[c] + ev.y * linE[8 + c] + ev.z * linE[16 + c] + ev.w * linE[24 + c];
    float a0 = 0.f, a1 = 0.f;
    #pragma unroll
    for (int a = 0; a < 4; ++a) {
        a0 += eh[a]     * att[2 * DD + a];
        a1 += eh[4 + a] * att[(2 * DD + AA) + 2 * DD + a];
    }
    ae.x = a0; ae.y = a1;
    enext.x = fmaxf(0.5f * (eh[0] + eh[4]), 0.f);
    enext.y = fmaxf(0.5f * (eh[1] + eh[5]), 0.f);
    enext.z = fmaxf(0.5f * (eh[2] + eh[6]), 0.f);
    enext.w = fmaxf(0.5f * (eh[3] + eh[7]), 0.f);
}

__global__ __launch_bounds__(256) void prep_fused(
        const float* __restrict__ ein, const int2* __restrict__ perm2,
        const float* __restrict__ linE0, const float* __restrict__ att0,
        const float* __restrict__ linE1, const float* __restrict__ att1,
        const float* __restrict__ linE2, const float* __restrict__ att2,
        int* __restrict__ asrc,
        float2* __restrict__ ae0, float2* __restrict__ ae1, float2* __restrict__ ae2,
        int E, int ebE,
        const float* __restrict__ X, uint2* __restrict__ As, int N, int ebA,
        const float* __restrict__ W0, const float* __restrict__ W1,
        const float* __restrict__ W2, unsigned short* __restrict__ Bs) {
    int b = blockIdx.x;
    if (b < ebE) {
        int p = b * 256 + threadIdx.x;
        if (p >= E) return;
        int2 pe = perm2[p];                    // coalesced
        asrc[p] = pe.y;                        // coalesced 4B
        float4 ev = ((const float4*)ein)[pe.x];// random 16B read (L3-resident)
        float2 ae; float4 en;
        edge_stage(ev, linE0, att0, ae, en); ae0[p] = ae;
        edge_stage(en, linE1, att1, ae, ev); ae1[p] = ae;
        edge_stage(ev, linE2, att2, ae, en); ae2[p] = ae;
    } else if (b < ebE + ebA) {
        int t = (b - ebE) * 256 + threadIdx.x;
        if (t >= N * 32) return;
        int r = t >> 5, kq4 = t & 31;
        float4 v = ((const float4*)X)[t];
        int g = r >> 4, m = r & 15;
        int ks = kq4 >> 3, q = (kq4 >> 1) & 3;
        int cell = ((g * 4 + ks) * 4 + q) * 16 + m;
        As[cell * 2 + (kq4 & 1)] = pack_bf16x4(v.x, v.y, v.z, v.w);
    } else {
        int t = (b - ebE - ebA) * 256 + threadIdx.x;
        if (t >= 3 * 128 * 64) return;
        int l = t / (128 * 64);
        int r = t - l * (128 * 64);
        const float* W = (l == 0) ? W0 : (l == 1) ? W1 : W2;
        unsigned short* B = Bs + (size_t)l * 128 * 256;
        int k = r >> 6, c4g = r & 63;
        float4 v = ((const float4*)W)[r];
        int ct = c4g >> 2, n0 = (c4g & 3) * 4;
        int ks = k >> 5, q = (k >> 3) & 3, j = k & 7;
        int cellbase = ((ct * 4 + ks) * 4 + q) * 16 + n0;
        B[(cellbase + 0) * 8 + j] = f2bf(v.x);
        B[(cellbase + 1) * 8 + j] = f2bf(v.y);
        B[(cellbase + 2) * 8 + j] = f2bf(v.z);
        B[(cellbase + 3) * 8 + j] = f2bf(v.w);
    }
}

// ---------------------------------------------------------------------------
// MFMA GEMM + fused epilogue. One wave per (16-row group, head-half).
// Emits xslice (slice-major bf16: slice s = feature cols [16s,16s+16) of each
// head; 64 B/node/slice, 3.2 MB/slice — fits one XCD L2) and attention logits.
// xslice element: node entry = 8 uint2: [0..3]=head0 16 bf16, [4..7]=head1.
// ---------------------------------------------------------------------------

__global__ __launch_bounds__(256) void gemm_mfma(const short8* __restrict__ As,
                                                 const short8* __restrict__ Bs,
                                                 const float* __restrict__ bias,
                                                 const float* __restrict__ att,
                                                 uint2* __restrict__ xslice,
                                                 float* __restrict__ aiaj, int Ngroups, int N) {
    __shared__ __align__(16) unsigned short sh[4][16 * 132];
    int w = threadIdx.x >> 6;
    int flat = blockIdx.x * 4 + w;
    int wid = flat >> 1, half = flat & 1;
    int lane = threadIdx.x & 63;
    if (wid >= Ngroups) return;
    int q = lane >> 4, m = lane & 15;

    const short8* Ag = As + (size_t)wid * 256;
    f32x4 acc[8];
    #pragma unroll
    for (int c8 = 0; c8 < 8; ++c8) acc[c8] = (f32x4){0.f, 0.f, 0.f, 0.f};

    #pragma unroll
    for (int ks = 0; ks < 4; ++ks) {
        short8 a = Ag[ks * 64 + lane];
        #pragma unroll
        for (int c8 = 0; c8 < 8; ++c8) {
            short8 b = Bs[(half * 8 + c8) * 256 + ks * 64 + lane];
            acc[c8] = __builtin_amdgcn_mfma_f32_16x16x32_bf16(a, b, acc[c8], 0, 0, 0);
        }
    }

    const float* atth = att + half * (2 * DD + AA);
    float ai[4] = {}, aj[4] = {};
    #pragma unroll
    for (int c8 = 0; c8 < 8; ++c8) {
        int col = c8 * 16 + m;
        float aS = atth[col];
        float aD = atth[DD + col];
        float bv = bias[(half * 8 + c8) * 16 + m];
        #pragma unroll
        for (int reg = 0; reg < 4; ++reg) {
            float val = acc[c8][reg] + bv;
            sh[w][(q * 4 + reg) * 132 + col] = f2bf(val);
            ai[reg] += val * aS;
            aj[reg] += val * aD;
        }
    }
    #pragma unroll
    for (int o = 1; o < 16; o <<= 1) {
        #pragma unroll
        for (int reg = 0; reg < 4; ++reg) {
            ai[reg] += __shfl_xor(ai[reg], o);
            aj[reg] += __shfl_xor(aj[reg], o);
        }
    }
    if (m == 0) {
        #pragma unroll
        for (int reg = 0; reg < 4; ++reg) {
            int row = wid * 16 + q * 4 + reg;
            aiaj[row * 4 + half] = ai[reg];
            aiaj[row * 4 + 2 + half] = aj[reg];
        }
    }
    // LDS tile -> slice-major store: slice ct, 16 nodes x 32 B (this head's half)
    int nl = lane >> 2, off = lane & 3;
    #pragma unroll
    for (int ct = 0; ct < 8; ++ct) {
        uint2 v = *(const uint2*)&sh[w][nl * 132 + ct * 16 + off * 4];
        xslice[((size_t)ct * N + wid * 16 + nl) * 8 + half * 4 + off] = v;
    }
}

// ---------------------------------------------------------------------------
// Per-layer softmax weights + denominators: one wave per dst node.
// aiaj table is 800 KB (L2-resident) -> cheap random gathers.
// Writes alpha[p]=(e0,e1) coalesced, denom[d], zeroes pdots on last layer.
// ---------------------------------------------------------------------------

__global__ __launch_bounds__(256) void denom_kernel(const float* __restrict__ aiaj,
                                                    const float2* __restrict__ ae,
                                                    const int* __restrict__ row_off,
                                                    const int* __restrict__ asrc,
                                                    float2* __restrict__ alpha,
                                                    float2* __restrict__ denom,
                                                    float* __restrict__ pdots, int N) {
    int w = threadIdx.x >> 6;
    int d = blockIdx.x * 4 + w;
    int lane = threadIdx.x & 63;
    if (d >= N) return;
    int s0 = row_off[d], s1 = row_off[d + 1];
    int deg = s1 - s0;
    const float2* aiaj2 = (const float2*)aiaj;
    float2 ajv = aiaj2[d * 2 + 1];
    float den0 = 0.f, den1 = 0.f;
    for (int c = 0; c < deg; c += 64) {
        if (c + lane < deg) {
            int p = s0 + c + lane;
            int s = asrc[p];
            float2 aiv = aiaj2[s * 2];
            float2 aev = ae[p];
            float a0 = aiv.x + ajv.x + aev.x; a0 = a0 > 0.f ? a0 : 0.2f * a0;
            float a1 = aiv.y + ajv.y + aev.y; a1 = a1 > 0.f ? a1 : 0.2f * a1;
            float e0 = __expf(a0), e1 = __expf(a1);
            den0 += e0; den1 += e1;
            float2 al; al.x = e0; al.y = e1;
            alpha[p] = al;
        }
    }
    #pragma unroll
    for (int o = 32; o; o >>= 1) {
        den0 += __shfl_xor(den0, o);
        den1 += __shfl_xor(den1, o);
    }
    if (lane == 0) {
        float2 dn;
        dn.x = (deg == 0) ? 1.f : den0;
        dn.y = (deg == 0) ? 1.f : den1;
        denom[d] = dn;
        if (pdots) pdots[d] = 0.f;
    }
}

// ---------------------------------------------------------------------------
// Sliced aggregation: slice = blockIdx & 7 -> same XCD under round-robin
// dispatch, so each XCD's L2 holds its 3.2 MB slice (random gathers = L2 hit).
// Wave = one (dst, slice): 8 edges x 8 lanes, 64 B line per edge-gather.
// ---------------------------------------------------------------------------

__global__ __launch_bounds__(256) void agg_slice(const uint2* __restrict__ xslice,
                                                 const float2* __restrict__ alpha,
                                                 const int* __restrict__ asrc,
                                                 const int* __restrict__ row_off,
                                                 const float2* __restrict__ denom,
                                                 uint2* __restrict__ hshuf,
                                                 const float* __restrict__ fw,
                                                 float* __restrict__ pdots, int N) {
    int b = blockIdx.x;
    int s = b & 7;
    int w = threadIdx.x >> 6;
    int d = (b >> 3) * 4 + w;
    int lane = threadIdx.x & 63;
    if (d >= N) return;
    int eg = lane >> 3, f = lane & 7;
    int s0 = row_off[d], s1 = row_off[d + 1];
    int deg = s1 - s0;
    const uint2* Xs = xslice + (size_t)s * N * 8;
    float4 xd = unpack_bf16x4(Xs[(size_t)d * 8 + f]);

    float4 acc = {0.f, 0.f, 0.f, 0.f};
    for (int c = 0; c < deg; c += 8) {
        float2 w2 = {0.f, 0.f};
        int sn = 0;
        if (c + eg < deg) {
            int p = s0 + c + eg;
            w2 = alpha[p];
            sn = asrc[p];
        }
        float wgt = (f < 4) ? w2.x : w2.y;
        float4 xv = unpack_bf16x4(Xs[(size_t)sn * 8 + f]);
        acc.x += wgt * xv.x; acc.y += wgt * xv.y;
        acc.z += wgt * xv.z; acc.w += wgt * xv.w;
    }
    // reduce over the 8 edge-groups
    #pragma unroll
    for (int o = 8; o < 64; o <<= 1) {
        acc.x += __shfl_xor(acc.x, o);
        acc.y += __shfl_xor(acc.y, o);
        acc.z += __shfl_xor(acc.z, o);
        acc.w += __shfl_xor(acc.w, o);
    }
    float2 dn = denom[d];
    float inv = 1.0f / ((f < 4) ? dn.x : dn.y);
    float4 v;
    v.x = acc.x * inv + xd.x;
    v.y = acc.y * inv + xd.y;
    v.z = acc.z * inv + xd.z;
    v.w = acc.w * inv + xd.w;
    // head mean: partner lane f^4 (within eg==0 group)
    float4 o2;
    o2.x = __shfl_xor(v.x, 4);
    o2.y = __shfl_xor(v.y, 4);
    o2.z = __shfl_xor(v.z, 4);
    o2.w = __shfl_xor(v.w, 4);
    if (lane < 4) {   // eg==0, f=lane covers h feats [16s+f*4, +4)
        float4 r;
        r.x = fmaxf(0.5f * (v.x + o2.x), 0.f);
        r.y = fmaxf(0.5f * (v.y + o2.y), 0.f);
        r.z = fmaxf(0.5f * (v.z + o2.z), 0.f);
        r.w = fmaxf(0.5f * (v.w + o2.w), 0.f);
        int L = s * 4 + lane;              // orig-lane equivalent (0..31)
        if (hshuf) {
            int g = d >> 4, m = d & 15;
            int ks = L >> 3, q = (L >> 1) & 3, bb = L & 1;
            int cell = ((g * 4 + ks) * 4 + q) * 16 + m;
            hshuf[cell * 2 + bb] = pack_bf16x4(r.x, r.y, r.z, r.w);
        }
        if (pdots) {
            float4 wv = ((const float4*)fw)[L];
            float pd = r.x * wv.x + r.y * wv.y + r.z * wv.z + r.w * wv.w;
            pd += __shfl_xor(pd, 1);
            pd += __shfl_xor(pd, 2);
            if (lane == 0) atomicAdd(&pdots[d], pd);
        }
    }
}

// ---------------------------------------------------------------------------
// Final pooling: segment-sum of per-node dots (batch is sorted)
// ---------------------------------------------------------------------------

__global__ __launch_bounds__(256) void segpool_kernel(const float* __restrict__ p,
                                                      const int* __restrict__ batch,
                                                      float* __restrict__ y, int N, int G) {
    __shared__ float bins[128];
    int t = threadIdx.x;
    if (t < G) bins[t] = 0.f;
    __syncthreads();
    int per = (N + gridDim.x - 1) / gridDim.x;
    int lo = blockIdx.x * per;
    int hi = min(lo + per, N);
    float acc = 0.f;
    int key = -1;
    for (int i = lo + t; i < hi; i += 256) {
        int k = batch[i];
        float v = p[i];
        if (k != key) {
            if (key >= 0) atomicAdd(&bins[key], acc);
            key = k;
            acc = 0.f;
        }
        acc += v;
    }
    if (key >= 0) atomicAdd(&bins[key], acc);
    __syncthreads();
    if (t < G && bins[t] != 0.f) atomicAdd(&y[t], bins[t]);
}

// ---------------------------------------------------------------------------
// Host side
// ---------------------------------------------------------------------------

extern "C" void kernel_launch(void* const* d_in, const int* in_sizes, int n_in,
                              void* d_out, int out_size, void* d_ws, size_t ws_size,
                              hipStream_t stream) {
    const float* x     = (const float*)d_in[0];
    const int*   ei    = (const int*)d_in[1];
    const float* eattr = (const float*)d_in[2];
    const int*   batch = (const int*)d_in[3];
    const float* fw    = (const float*)d_in[16];
    const float* fb    = (const float*)d_in[17];
    float* y = (float*)d_out;

    const int N = in_sizes[0] / DD;     // 50000  (divisible by 16)
    const int E = in_sizes[1] / 2;      // 800000
    const int G = out_size;             // 128

    const int* src = ei;
    const int* dst = ei + E;

    char* ws = (char*)d_ws;
    size_t off = 0;
    auto carve = [&](size_t bytes) {
        char* p = ws + off;
        off += (bytes + 255) & ~(size_t)255;
        return p;
    };
    uint2*  xslice  = (uint2*)carve((size_t)N * 64 * 8);    // slice-major bf16 [8][N][64B]
    uint2*  S0      = (uint2*)carve((size_t)N * 128 * 2);   // shuffled bf16 A (ping)
    uint2*  S1      = (uint2*)carve((size_t)N * 128 * 2);   // shuffled bf16 A (pong)
    unsigned short* Bs = (unsigned short*)carve((size_t)3 * 128 * 256 * 2);
    float2* ae0     = (float2*)carve((size_t)E * 2 * 4);
    float2* ae1     = (float2*)carve((size_t)E * 2 * 4);
    float2* ae2     = (float2*)carve((size_t)E * 2 * 4);
    float2* alpha   = (float2*)carve((size_t)E * 8);
    float*  aiaj    = (float*)carve((size_t)N * 4 * 4);
    float2* denomb  = (float2*)carve((size_t)N * 8);
    int*    row_off = (int*)carve((size_t)(N + 1) * 4);
    int*    cnt     = (int*)carve((size_t)N * 4);
    int*    rank    = (int*)carve((size_t)E * 4);
    int2*   perm2   = (int2*)carve((size_t)E * 8);
    int*    asrc    = (int*)carve((size_t)E * 4);
    float*  pdots   = (float*)carve((size_t)N * 4);
    int*    bsum    = (int*)carve((size_t)256 * 4);

    const int NB = (N + 1023) / 1024;   // 49 <= 64
    const int Ngroups = N / 16;         // 3125
    const int eb = (E + 255) / 256;     // 3125

    // ---- CSR build: rank (1 atomic pass) -> scans -> perm (no atomics) ----
    hipMemsetAsync(cnt, 0, (size_t)N * 4, stream);
    rank_kernel<<<eb, 256, 0, stream>>>(dst, cnt, rank, E);
    scan1<<<NB, 256, 0, stream>>>(cnt, bsum, N, y, fb);
    scan3<<<NB, 256, 0, stream>>>(cnt, bsum, row_off, N, NB, E);
    perm_kernel<<<eb, 256, 0, stream>>>(src, dst, rank, row_off, perm2, E);

    // ---- fused prep: edge transform + asrc + pack_a0 + pack_w3 ----
    const int ebA = (N * 32 + 255) / 256;
    const int ebW = (3 * 128 * 64 + 255) / 256;
    prep_fused<<<eb + ebA + ebW, 256, 0, stream>>>(
        eattr, perm2,
        (const float*)d_in[5], (const float*)d_in[6],
        (const float*)d_in[9], (const float*)d_in[10],
        (const float*)d_in[13], (const float*)d_in[14],
        asrc, ae0, ae1, ae2, E, eb,
        x, S0, N, ebA,
        (const float*)d_in[4], (const float*)d_in[8], (const float*)d_in[12], Bs);

    // ---- 3 GAT layers ----
    int gemm_blocks = (Ngroups * 2 + 3) / 4;
    int nd_blocks = (N + 3) / 4;
    int slice_blocks = nd_blocks * 8;
    float2* aes[3] = {ae0, ae1, ae2};
    uint2* Ain[3]  = {S0, S1, S0};
    uint2* Aout[3] = {S1, S0, nullptr};

    for (int l = 0; l < 3; ++l) {
        const float* att  = (const float*)d_in[6 + 4 * l];
        const float* bias = (const float*)d_in[7 + 4 * l];
        const short8* Bl  = (const short8*)(Bs + (size_t)l * 128 * 256);
        float* pd = (l == 2) ? pdots : nullptr;

        gemm_mfma<<<gemm_blocks, 256, 0, stream>>>((const short8*)Ain[l], Bl,
                                                   bias, att, xslice, aiaj, Ngroups, N);
        denom_kernel<<<nd_blocks, 256, 0, stream>>>(aiaj, aes[l], row_off, asrc,
                                                    alpha, denomb, pd, N);
        agg_slice<<<slice_blocks, 256, 0, stream>>>(xslice, alpha, asrc, row_off,
                                                    denomb, Aout[l], fw, pd, N);
    }

    // ---- pooling ----
    segpool_kernel<<<128, 256, 0, stream>>>(pdots, batch, y, N, G);
}

// Round 13
// 431.339 us; speedup vs baseline: 1.7841x; 1.7841x over previous
//
#include <hip/hip_runtime.h>
#include <hip/hip_bf16.h>

// Problem constants (match reference)
#define DD 128      // feature dim
#define AA 4        // edge attr dim
#define HH 2        // heads

typedef short short8 __attribute__((ext_vector_type(8)));
typedef float f32x4 __attribute__((ext_vector_type(4)));

// bf16 pack/unpack (RNE)
__device__ inline unsigned short f2bf(float f) {
    unsigned u = __float_as_uint(f);
    unsigned r = (u + 0x7fffu + ((u >> 16) & 1u)) >> 16;
    return (unsigned short)r;
}
__device__ inline float4 unpack_bf16x4(uint2 v) {
    float4 r;
    r.x = __uint_as_float(v.x << 16);
    r.y = __uint_as_float(v.x & 0xffff0000u);
    r.z = __uint_as_float(v.y << 16);
    r.w = __uint_as_float(v.y & 0xffff0000u);
    return r;
}
__device__ inline uint2 pack_bf16x4(float a, float b, float c, float d) {
    uint2 p;
    p.x = (unsigned)f2bf(a) | ((unsigned)f2bf(b) << 16);
    p.y = (unsigned)f2bf(c) | ((unsigned)f2bf(d) << 16);
    return p;
}

// ---------------------------------------------------------------------------
// CSR build, pass 1: histogram + per-edge rank in ONE atomic pass.
// ---------------------------------------------------------------------------

__global__ void rank_kernel(const int* __restrict__ dst, int* __restrict__ cnt,
                            int* __restrict__ rank, int E) {
    int e = blockIdx.x * blockDim.x + threadIdx.x;
    if (e < E) rank[e] = atomicAdd(&cnt[dst[e]], 1);
}

// scan1: per-1024-chunk sums; block 0 also inits y = fb
__global__ __launch_bounds__(256) void scan1(const int* __restrict__ cnt,
                                             int* __restrict__ bsum, int N,
                                             float* __restrict__ y,
                                             const float* __restrict__ fb) {
    __shared__ int wsh[4];
    int b = blockIdx.x, t = threadIdx.x;
    int lane = t & 63, w = t >> 6;
    if (b == 0 && t < 128) y[t] = fb[0];
    int base = b * 1024;
    int v = 0;
    #pragma unroll
    for (int i = 0; i < 4; ++i) {
        int idx = base + i * 256 + t;
        v += (idx < N) ? cnt[idx] : 0;
    }
    #pragma unroll
    for (int o = 32; o; o >>= 1) v += __shfl_xor(v, o);
    if (lane == 0) wsh[w] = v;
    __syncthreads();
    if (t == 0) bsum[b] = wsh[0] + wsh[1] + wsh[2] + wsh[3];
}

// scan3: final per-element exclusive prefix; each block wave-scans bsum (NB<=64)
__global__ __launch_bounds__(256) void scan3(const int* __restrict__ cnt,
                                             const int* __restrict__ bsum,
                                             int* __restrict__ row_off,
                                             int N, int NB, int E) {
    __shared__ int wtot[4];
    __shared__ int carry;
    int b = blockIdx.x, t = threadIdx.x;
    int lane = t & 63, w = t >> 6;
    if (w == 0) {
        int v = (lane < NB) ? bsum[lane] : 0;
        int x = v;
        #pragma unroll
        for (int o = 1; o < 64; o <<= 1) {
            int u = __shfl_up(x, o);
            if (lane >= o) x += u;
        }
        int base = (b == 0) ? 0 : __shfl(x, b - 1);
        if (lane == 0) carry = base;
    }
    if (b == 0 && t == 0) row_off[N] = E;
    __syncthreads();
    int base = b * 1024;
    #pragma unroll
    for (int it = 0; it < 4; ++it) {
        int idx = base + it * 256 + t;
        int v = (idx < N) ? cnt[idx] : 0;
        int x = v;
        #pragma unroll
        for (int o = 1; o < 64; o <<= 1) {
            int u = __shfl_up(x, o);
            if (lane >= o) x += u;
        }
        if (lane == 63) wtot[w] = x;
        __syncthreads();
        int woff = 0;
        for (int i = 0; i < w; ++i) woff += wtot[i];
        int c = carry;
        __syncthreads();
        if (t == 255) carry = c + woff + x;
        int ex = c + woff + x - v;
        if (idx < N) row_off[idx] = ex;
        __syncthreads();
    }
}

// CSR build, pass 2: one random 8B write of (edge id, src) per edge.
__global__ void perm_kernel(const int* __restrict__ src, const int* __restrict__ dst,
                            const int* __restrict__ rank,
                            const int* __restrict__ row_off,
                            int2* __restrict__ perm2, int E) {
    int e = blockIdx.x * blockDim.x + threadIdx.x;
    if (e >= E) return;
    int2 v; v.x = e; v.y = src[e];
    perm2[row_off[dst[e]] + rank[e]] = v;
}

// ---------------------------------------------------------------------------
// Fused prep: edge transform (all 3 layers, CSR-ordered) + asrc extraction +
// pack_a0 + pack_w3, via blockIdx range split.
// ---------------------------------------------------------------------------

__device__ inline void edge_stage(const float4& ev, const float* __restrict__ linE,
                                  const float* __restrict__ att, float2& ae, float4& enext) {
    float eh[8];
    #pragma unroll
    for (int c = 0; c < 8; ++c)
        eh[c] = ev.x * linE[c] + ev.y * linE[8 + c] + ev.z * linE[16 + c] + ev.w * linE[24 + c];
    float a0 = 0.f, a1 = 0.f;
    #pragma unroll
    for (int a = 0; a < 4; ++a) {
        a0 += eh[a]     * att[2 * DD + a];
        a1 += eh[4 + a] * att[(2 * DD + AA) + 2 * DD + a];
    }
    ae.x = a0; ae.y = a1;
    enext.x = fmaxf(0.5f * (eh[0] + eh[4]), 0.f);
    enext.y = fmaxf(0.5f * (eh[1] + eh[5]), 0.f);
    enext.z = fmaxf(0.5f * (eh[2] + eh[6]), 0.f);
    enext.w = fmaxf(0.5f * (eh[3] + eh[7]), 0.f);
}

__global__ __launch_bounds__(256) void prep_fused(
        const float* __restrict__ ein, const int2* __restrict__ perm2,
        const float* __restrict__ linE0, const float* __restrict__ att0,
        const float* __restrict__ linE1, const float* __restrict__ att1,
        const float* __restrict__ linE2, const float* __restrict__ att2,
        int* __restrict__ asrc,
        float2* __restrict__ ae0, float2* __restrict__ ae1, float2* __restrict__ ae2,
        int E, int ebE,
        const float* __restrict__ X, uint2* __restrict__ As, int N, int ebA,
        const float* __restrict__ W0, const float* __restrict__ W1,
        const float* __restrict__ W2, unsigned short* __restrict__ Bs) {
    int b = blockIdx.x;
    if (b < ebE) {
        int p = b * 256 + threadIdx.x;
        if (p >= E) return;
        int2 pe = perm2[p];                    // coalesced
        asrc[p] = pe.y;                        // coalesced 4B
        float4 ev = ((const float4*)ein)[pe.x];// random 16B read (L3-resident)
        float2 ae; float4 en;
        edge_stage(ev, linE0, att0, ae, en); ae0[p] = ae;
        edge_stage(en, linE1, att1, ae, ev); ae1[p] = ae;
        edge_stage(ev, linE2, att2, ae, en); ae2[p] = ae;
    } else if (b < ebE + ebA) {
        int t = (b - ebE) * 256 + threadIdx.x;
        if (t >= N * 32) return;
        int r = t >> 5, kq4 = t & 31;
        float4 v = ((const float4*)X)[t];
        int g = r >> 4, m = r & 15;
        int ks = kq4 >> 3, q = (kq4 >> 1) & 3;
        int cell = ((g * 4 + ks) * 4 + q) * 16 + m;
        As[cell * 2 + (kq4 & 1)] = pack_bf16x4(v.x, v.y, v.z, v.w);
    } else {
        int t = (b - ebE - ebA) * 256 + threadIdx.x;
        if (t >= 3 * 128 * 64) return;
        int l = t / (128 * 64);
        int r = t - l * (128 * 64);
        const float* W = (l == 0) ? W0 : (l == 1) ? W1 : W2;
        unsigned short* B = Bs + (size_t)l * 128 * 256;
        int k = r >> 6, c4g = r & 63;
        float4 v = ((const float4*)W)[r];
        int ct = c4g >> 2, n0 = (c4g & 3) * 4;
        int ks = k >> 5, q = (k >> 3) & 3, j = k & 7;
        int cellbase = ((ct * 4 + ks) * 4 + q) * 16 + n0;
        B[(cellbase + 0) * 8 + j] = f2bf(v.x);
        B[(cellbase + 1) * 8 + j] = f2bf(v.y);
        B[(cellbase + 2) * 8 + j] = f2bf(v.z);
        B[(cellbase + 3) * 8 + j] = f2bf(v.w);
    }
}

// ---------------------------------------------------------------------------
// MFMA GEMM + fused epilogue. One wave per (16-row group, head-half):
// 8 col-tiles of 16; K=128 in 4 steps of 32. Emits bf16 xhb (LDS transpose,
// wave-private -> no barrier) and this half's attention logits.
// ---------------------------------------------------------------------------

__global__ __launch_bounds__(256) void gemm_mfma(const short8* __restrict__ As,
                                                 const short8* __restrict__ Bs,
                                                 const float* __restrict__ bias,
                                                 const float* __restrict__ att,
                                                 uint2* __restrict__ xhb,
                                                 float* __restrict__ aiaj, int Ngroups) {
    __shared__ __align__(16) unsigned short sh[4][16 * 132];
    int w = threadIdx.x >> 6;
    int flat = blockIdx.x * 4 + w;
    int wid = flat >> 1, half = flat & 1;
    int lane = threadIdx.x & 63;
    if (wid >= Ngroups) return;
    int q = lane >> 4, m = lane & 15;

    const short8* Ag = As + (size_t)wid * 256;
    f32x4 acc[8];
    #pragma unroll
    for (int c8 = 0; c8 < 8; ++c8) acc[c8] = (f32x4){0.f, 0.f, 0.f, 0.f};

    #pragma unroll
    for (int ks = 0; ks < 4; ++ks) {
        short8 a = Ag[ks * 64 + lane];
        #pragma unroll
        for (int c8 = 0; c8 < 8; ++c8) {
            short8 b = Bs[(half * 8 + c8) * 256 + ks * 64 + lane];
            acc[c8] = __builtin_amdgcn_mfma_f32_16x16x32_bf16(a, b, acc[c8], 0, 0, 0);
        }
    }

    const float* atth = att + half * (2 * DD + AA);
    float ai[4] = {}, aj[4] = {};
    #pragma unroll
    for (int c8 = 0; c8 < 8; ++c8) {
        int col = c8 * 16 + m;
        float aS = atth[col];
        float aD = atth[DD + col];
        float bv = bias[(half * 8 + c8) * 16 + m];
        #pragma unroll
        for (int reg = 0; reg < 4; ++reg) {
            float val = acc[c8][reg] + bv;
            sh[w][(q * 4 + reg) * 132 + col] = f2bf(val);
            ai[reg] += val * aS;
            aj[reg] += val * aD;
        }
    }
    #pragma unroll
    for (int o = 1; o < 16; o <<= 1) {
        #pragma unroll
        for (int reg = 0; reg < 4; ++reg) {
            ai[reg] += __shfl_xor(ai[reg], o);
            aj[reg] += __shfl_xor(aj[reg], o);
        }
    }
    if (m == 0) {
        #pragma unroll
        for (int reg = 0; reg < 4; ++reg) {
            int row = wid * 16 + q * 4 + reg;
            aiaj[row * 4 + half] = ai[reg];
            aiaj[row * 4 + 2 + half] = aj[reg];
        }
    }
    #pragma unroll
    for (int r2 = 0; r2 < 8; ++r2) {
        int row = r2 * 2 + (lane >> 5);
        uint2 v = *(const uint2*)&sh[w][row * 132 + (lane & 31) * 4];
        xhb[(size_t)(wid * 16 + row) * 64 + half * 32 + (lane & 31)] = v;
    }
}

// ---------------------------------------------------------------------------
// Aggregation: 4 waves per block, each wave owns one dst node (wave-private
// LDS, barrier-free). Inner loop: 2 edges/iteration, uint4 (16B/lane) gathers
// — lanes 0-31 edge j (8 feats/lane), lanes 32-63 edge j+1; combine via one
// xor-32 shuffle. Single-pass softmax; bf16 payload & skip.
// ---------------------------------------------------------------------------

__global__ __launch_bounds__(256) void aggregate(const uint2* __restrict__ xhb,
                                                 const float* __restrict__ aiaj,
                                                 const float2* __restrict__ ae,
                                                 const int* __restrict__ row_off,
                                                 const int* __restrict__ asrc,
                                                 uint2* __restrict__ hshuf,
                                                 const float* __restrict__ fw,
                                                 float* __restrict__ pdots, int N) {
    int w = threadIdx.x >> 6;
    int d = blockIdx.x * 4 + w;
    int lane = threadIdx.x & 63;
    if (d >= N) return;
    int s0 = row_off[d], s1 = row_off[d + 1];
    int deg = s1 - s0;
    const float2* aiaj2 = (const float2*)aiaj;
    float2 ajv = aiaj2[d * 2 + 1];   // (aj0, aj1)
    const uint4* X4 = (const uint4*)xhb;   // 32 uint4 per 256-col row

    int half = lane >> 5;    // edge of the pair
    int li = lane & 31;      // 16B chunk within row (8 feats)
    int headp = li >> 4;     // 0: feats<128 (head0), 1: head1

    uint4 xdp = X4[(size_t)d * 32 + li];   // skip-row chunk (early)

    __shared__ float lex[4][64][2];
    __shared__ int lsrc[4][64];
    float a[8] = {};
    float den0 = 0.f, den1 = 0.f;

    for (int c = 0; c < deg; c += 64) {
        int n = min(64, deg - c);
        if (lane < n) {
            int p = s0 + c + lane;
            int s = asrc[p];
            float2 aiv = aiaj2[s * 2];
            float2 aev = ae[p];
            float a0 = aiv.x + ajv.x + aev.x; a0 = a0 > 0.f ? a0 : 0.2f * a0;
            float a1 = aiv.y + ajv.y + aev.y; a1 = a1 > 0.f ? a1 : 0.2f * a1;
            float e0 = __expf(a0), e1 = __expf(a1);
            den0 += e0; den1 += e1;
            lex[w][lane][0] = e0; lex[w][lane][1] = e1;
            lsrc[w][lane] = s;
        } else if (lane == n) {          // pad for odd tail (weight 0)
            lex[w][lane][0] = 0.f; lex[w][lane][1] = 0.f;
            lsrc[w][lane] = 0;
        }
        int n2 = (n + 1) & ~1;
        for (int j = 0; j < n2; j += 2) {
            float wgt = lex[w][j + half][headp];
            int sn = lsrc[w][j + half];
            uint4 xv = X4[(size_t)sn * 32 + li];
            a[0] += wgt * __uint_as_float(xv.x << 16);
            a[1] += wgt * __uint_as_float(xv.x & 0xffff0000u);
            a[2] += wgt * __uint_as_float(xv.y << 16);
            a[3] += wgt * __uint_as_float(xv.y & 0xffff0000u);
            a[4] += wgt * __uint_as_float(xv.z << 16);
            a[5] += wgt * __uint_as_float(xv.z & 0xffff0000u);
            a[6] += wgt * __uint_as_float(xv.w << 16);
            a[7] += wgt * __uint_as_float(xv.w & 0xffff0000u);
        }
    }

    // combine the two edge-halves
    #pragma unroll
    for (int k = 0; k < 8; ++k) a[k] += __shfl_xor(a[k], 32);
    #pragma unroll
    for (int o = 32; o; o >>= 1) {
        den0 += __shfl_xor(den0, o);
        den1 += __shfl_xor(den1, o);
    }
    float den = headp ? den1 : den0;
    if (deg == 0) den = 1.0f;
    float inv = 1.0f / den;

    float v[8];
    v[0] = a[0] * inv + __uint_as_float(xdp.x << 16);
    v[1] = a[1] * inv + __uint_as_float(xdp.x & 0xffff0000u);
    v[2] = a[2] * inv + __uint_as_float(xdp.y << 16);
    v[3] = a[3] * inv + __uint_as_float(xdp.y & 0xffff0000u);
    v[4] = a[4] * inv + __uint_as_float(xdp.z << 16);
    v[5] = a[5] * inv + __uint_as_float(xdp.z & 0xffff0000u);
    v[6] = a[6] * inv + __uint_as_float(xdp.w << 16);
    v[7] = a[7] * inv + __uint_as_float(xdp.w & 0xffff0000u);

    // head mean: lane li (<16) pairs with li^16 (same feat slot, other head)
    float r[8];
    #pragma unroll
    for (int k = 0; k < 8; ++k) {
        float o2 = __shfl_xor(v[k], 16);
        r[k] = fmaxf(0.5f * (v[k] + o2), 0.f);
    }
    if (lane < 16) {   // holds h feats [8*lane, 8*lane+8)
        if (hshuf) {
            int g = d >> 4, m = d & 15;
            int L0 = lane * 2, L1 = L0 + 1;  // orig 4-feat lanes
            int ks0 = L0 >> 3, q0 = (L0 >> 1) & 3;
            int cell0 = ((g * 4 + ks0) * 4 + q0) * 16 + m;
            hshuf[cell0 * 2 + 0] = pack_bf16x4(r[0], r[1], r[2], r[3]);
            int ks1 = L1 >> 3, q1 = (L1 >> 1) & 3;
            int cell1 = ((g * 4 + ks1) * 4 + q1) * 16 + m;
            hshuf[cell1 * 2 + 1] = pack_bf16x4(r[4], r[5], r[6], r[7]);
        }
        if (pdots) {
            const float4* fw4 = (const float4*)fw;
            float4 w0 = fw4[lane * 2], w1 = fw4[lane * 2 + 1];
            float pd = r[0] * w0.x + r[1] * w0.y + r[2] * w0.z + r[3] * w0.w
                     + r[4] * w1.x + r[5] * w1.y + r[6] * w1.z + r[7] * w1.w;
            #pragma unroll
            for (int o = 8; o; o >>= 1) pd += __shfl_xor(pd, o);
            if (lane == 0) pdots[d] = pd;
        }
    }
}

// ---------------------------------------------------------------------------
// Final pooling: segment-sum of per-node dots (batch is sorted)
// ---------------------------------------------------------------------------

__global__ __launch_bounds__(256) void segpool_kernel(const float* __restrict__ p,
                                                      const int* __restrict__ batch,
                                                      float* __restrict__ y, int N, int G) {
    __shared__ float bins[128];
    int t = threadIdx.x;
    if (t < G) bins[t] = 0.f;
    __syncthreads();
    int per = (N + gridDim.x - 1) / gridDim.x;
    int lo = blockIdx.x * per;
    int hi = min(lo + per, N);
    float acc = 0.f;
    int key = -1;
    for (int i = lo + t; i < hi; i += 256) {
        int k = batch[i];
        float v = p[i];
        if (k != key) {
            if (key >= 0) atomicAdd(&bins[key], acc);
            key = k;
            acc = 0.f;
        }
        acc += v;
    }
    if (key >= 0) atomicAdd(&bins[key], acc);
    __syncthreads();
    if (t < G && bins[t] != 0.f) atomicAdd(&y[t], bins[t]);
}

// ---------------------------------------------------------------------------
// Host side
// ---------------------------------------------------------------------------

extern "C" void kernel_launch(void* const* d_in, const int* in_sizes, int n_in,
                              void* d_out, int out_size, void* d_ws, size_t ws_size,
                              hipStream_t stream) {
    const float* x     = (const float*)d_in[0];
    const int*   ei    = (const int*)d_in[1];
    const float* eattr = (const float*)d_in[2];
    const int*   batch = (const int*)d_in[3];
    const float* fw    = (const float*)d_in[16];
    const float* fb    = (const float*)d_in[17];
    float* y = (float*)d_out;

    const int N = in_sizes[0] / DD;     // 50000  (divisible by 16)
    const int E = in_sizes[1] / 2;      // 800000
    const int G = out_size;             // 128

    const int* src = ei;
    const int* dst = ei + E;

    char* ws = (char*)d_ws;
    size_t off = 0;
    auto carve = [&](size_t bytes) {
        char* p = ws + off;
        off += (bytes + 255) & ~(size_t)255;
        return p;
    };
    uint2*  xhb     = (uint2*)carve((size_t)N * 256 * 2);   // bf16 features [N][256]
    uint2*  S0      = (uint2*)carve((size_t)N * 128 * 2);   // shuffled bf16 A (ping)
    uint2*  S1      = (uint2*)carve((size_t)N * 128 * 2);   // shuffled bf16 A (pong)
    unsigned short* Bs = (unsigned short*)carve((size_t)3 * 128 * 256 * 2);
    float2* ae0     = (float2*)carve((size_t)E * 2 * 4);
    float2* ae1     = (float2*)carve((size_t)E * 2 * 4);
    float2* ae2     = (float2*)carve((size_t)E * 2 * 4);
    float*  aiaj    = (float*)carve((size_t)N * 4 * 4);
    int*    row_off = (int*)carve((size_t)(N + 1) * 4);
    int*    cnt     = (int*)carve((size_t)N * 4);
    int*    rank    = (int*)carve((size_t)E * 4);
    int2*   perm2   = (int2*)carve((size_t)E * 8);
    int*    asrc    = (int*)carve((size_t)E * 4);
    float*  pdots   = (float*)carve((size_t)N * 4);
    int*    bsum    = (int*)carve((size_t)256 * 4);

    const int NB = (N + 1023) / 1024;   // 49 <= 64
    const int Ngroups = N / 16;         // 3125
    const int eb = (E + 255) / 256;     // 3125

    // ---- CSR build: rank (1 atomic pass) -> scans -> perm (no atomics) ----
    hipMemsetAsync(cnt, 0, (size_t)N * 4, stream);
    rank_kernel<<<eb, 256, 0, stream>>>(dst, cnt, rank, E);
    scan1<<<NB, 256, 0, stream>>>(cnt, bsum, N, y, fb);
    scan3<<<NB, 256, 0, stream>>>(cnt, bsum, row_off, N, NB, E);
    perm_kernel<<<eb, 256, 0, stream>>>(src, dst, rank, row_off, perm2, E);

    // ---- fused prep: edge transform + asrc + pack_a0 + pack_w3 ----
    const int ebA = (N * 32 + 255) / 256;
    const int ebW = (3 * 128 * 64 + 255) / 256;
    prep_fused<<<eb + ebA + ebW, 256, 0, stream>>>(
        eattr, perm2,
        (const float*)d_in[5], (const float*)d_in[6],
        (const float*)d_in[9], (const float*)d_in[10],
        (const float*)d_in[13], (const float*)d_in[14],
        asrc, ae0, ae1, ae2, E, eb,
        x, S0, N, ebA,
        (const float*)d_in[4], (const float*)d_in[8], (const float*)d_in[12], Bs);

    // ---- 3 GAT layers ----
    int gemm_blocks = (Ngroups * 2 + 3) / 4;
    int agg_blocks = (N + 3) / 4;
    float2* aes[3] = {ae0, ae1, ae2};
    uint2* Ain[3]  = {S0, S1, S0};
    uint2* Aout[3] = {S1, S0, nullptr};

    for (int l = 0; l < 3; ++l) {
        const float* att  = (const float*)d_in[6 + 4 * l];
        const float* bias = (const float*)d_in[7 + 4 * l];
        const short8* Bl  = (const short8*)(Bs + (size_t)l * 128 * 256);

        gemm_mfma<<<gemm_blocks, 256, 0, stream>>>((const short8*)Ain[l], Bl,
                                                   bias, att, xhb, aiaj, Ngroups);
        aggregate<<<agg_blocks, 256, 0, stream>>>(xhb, aiaj, aes[l], row_off, asrc,
                                                  Aout[l], fw, (l == 2) ? pdots : nullptr, N);
    }

    // ---- pooling ----
    segpool_kernel<<<128, 256, 0, stream>>>(pdots, batch, y, N, G);
}